// Round 2
// baseline (184.883 us; speedup 1.0000x reference)
//
#include <hip/hip_runtime.h>

// PositionWiseSpatialAttention — fused flash-style kernel, MI355X gfx950.
//
// For each g = (b,t) of 96: xr = x[b,:,t,:] (1024x64)
//   S = xr.xr^T / 8 ; attn = softmax(S) ; agg = (adj*attn).xr ; out = relu(agg.theta)
// Key facts exploited:
//  * scores bounded (|s| <~ 16) -> softmax without max-subtraction: single pass,
//    numerator Sum(adj*exp(s)*v) and denominator Sum(exp(s)) accumulated online.
//  * no fp32 MFMA on CDNA4 -> error-compensated split bf16 (hi+lo, 3 MFMAs per
//    product, ~2^-16 relative error ~= fp32) so validation vs fp32 ref is safe.
//  * 16x16x32 bf16 MFMA only (A: m=lane&15,k=quad*8+j; C: col=lane&15,
//    row=quad*4+reg -- HW-verified layouts).
// Block: 256 thr = 4 waves, 128 query rows (wave owns 32). 32-key tiles staged
// to LDS hi/lo in two layouts (K[key][d] for QK^T, V[d][key] for PV), strides
// picked for uniform bank-quad distribution on ds_read_b128. P=adj*exp round-
// trips LDS in fp32 (per-wave rows -> no barrier). Register-buffered global
// prefetch of next tile. Epilogue (agg/l @ theta, split, relu) overlays LDS.

#define NB    8
#define NT    12
#define NNODE 1024
#define ND    64
#define XROW  768   /* NT*ND: stride between consecutive n for fixed (b,t) */

typedef __bf16 bf16x8 __attribute__((ext_vector_type(8)));
typedef float  floatx4 __attribute__((ext_vector_type(4)));

#define MFMA(a,b,c) __builtin_amdgcn_mfma_f32_16x16x32_bf16((a),(b),(c),0,0,0)

// LDS layout (bytes); all row strides keep 16B alignment for b128 ops.
#define KSTRIDE 72   /* bf16 per K row: 144 B  (36 words -> quad stride 1 mod 8) */
#define VSTRIDE 40   /* bf16 per V row:  80 B  (20 words -> quad stride 5 mod 8) */
#define PSTRIDE 36   /* f32  per P row: 144 B */
#define AGSTRIDE 68  /* f32  per AG row (epilogue overlay) */
#define OFF_KHI 0
#define OFF_KLO 4608
#define OFF_VHI 9216
#define OFF_VLO 14336
#define OFF_P   19456
#define SMEM_BYTES (19456 + 128*PSTRIDE*4)   /* 37888; epilogue AG 128*68*4=34816 fits */

struct bfpair { __bf16 h, l; };

__device__ __forceinline__ bfpair splitf(float f) {
    // round-to-nearest-even split: f ~= h + l with h,l bf16 (error ~2^-17 |f|)
    bfpair r;
    unsigned u  = __builtin_bit_cast(unsigned, f);
    unsigned hu = (u + 0x7fffu + ((u >> 16) & 1u)) & 0xffff0000u;
    r.h = __builtin_bit_cast(__bf16, (unsigned short)(hu >> 16));
    float rem = f - __builtin_bit_cast(float, hu);
    unsigned ru = __builtin_bit_cast(unsigned, rem);
    ru += 0x7fffu + ((ru >> 16) & 1u);
    r.l = __builtin_bit_cast(__bf16, (unsigned short)(ru >> 16));
    return r;
}

__global__ void __launch_bounds__(256, 2)
spattn(const float* __restrict__ x, const float* __restrict__ adj,
       const float* __restrict__ theta, float* __restrict__ out)
{
    __shared__ __align__(16) char smem[SMEM_BYTES];
    __bf16* Khi = (__bf16*)(smem + OFF_KHI);
    __bf16* Klo = (__bf16*)(smem + OFF_KLO);
    __bf16* Vhi = (__bf16*)(smem + OFF_VHI);
    __bf16* Vlo = (__bf16*)(smem + OFF_VLO);
    float*  Pm  = (float*)(smem + OFF_P);

    const int tid  = threadIdx.x;
    const int wave = tid >> 6;
    const int lane = tid & 63;
    const int l16  = lane & 15;
    const int quad = lane >> 4;

    const int bx   = blockIdx.x;
    const int g    = bx >> 3;       // 0..95
    const int rblk = bx & 7;        // 0..7
    const int bb   = g / NT;
    const int tt   = g - bb * NT;
    const int row0 = rblk * 128;

    const float* xbase = x + (size_t)bb * (NNODE * XROW) + tt * ND;

    // ---- Q fragments (hi/lo), rows wave*32 .. +32, straight from global ----
    bf16x8 qhi[2][2], qlo[2][2];
    #pragma unroll
    for (int mt = 0; mt < 2; ++mt) {
        const float* qsrc = xbase + (size_t)(row0 + wave*32 + mt*16 + l16) * XROW;
        #pragma unroll
        for (int ks = 0; ks < 2; ++ks) {
            floatx4 f0 = *(const floatx4*)(qsrc + ks*32 + quad*8);
            floatx4 f1 = *(const floatx4*)(qsrc + ks*32 + quad*8 + 4);
            #pragma unroll
            for (int i = 0; i < 4; ++i) {
                bfpair p0 = splitf(f0[i]);
                qhi[mt][ks][i]   = p0.h; qlo[mt][ks][i]   = p0.l;
                bfpair p1 = splitf(f1[i]);
                qhi[mt][ks][4+i] = p1.h; qlo[mt][ks][4+i] = p1.l;
            }
        }
    }

    const floatx4 vzero = {0.f, 0.f, 0.f, 0.f};
    floatx4 acc[2][4];
    #pragma unroll
    for (int mt = 0; mt < 2; ++mt)
        #pragma unroll
        for (int dt = 0; dt < 4; ++dt)
            acc[mt][dt] = vzero;
    float lpart[2][4] = {{0.f,0.f,0.f,0.f},{0.f,0.f,0.f,0.f}};

    // staging maps: K-map (1 key x 8 d, b128 LDS writes), V-map (8 keys x 1 d)
    const int skey = tid >> 3;          // 0..31
    const int sd0  = (tid & 7) * 8;     // 0..56
    const int svd  = tid >> 2;          // 0..63
    const int svk0 = (tid & 3) * 8;     // 0..24
    floatx4 kf0, kf1;
    float vf[8];

    { // preload tile 0 into registers
        const float* ksrc = xbase + (size_t)skey * XROW + sd0;
        kf0 = *(const floatx4*)ksrc;
        kf1 = *(const floatx4*)(ksrc + 4);
        const float* vsrc = xbase + (size_t)svk0 * XROW + svd;
        #pragma unroll
        for (int i = 0; i < 8; ++i) vf[i] = vsrc[i * XROW];
    }

    for (int ct = 0; ct < 32; ++ct) {
        const int key0 = ct * 32;
        __syncthreads();                       // prior tile's LDS reads done
        { // store staged tile (split hi/lo) to LDS
            bf16x8 h, l;
            #pragma unroll
            for (int i = 0; i < 4; ++i) {
                bfpair p0 = splitf(kf0[i]); h[i]   = p0.h; l[i]   = p0.l;
                bfpair p1 = splitf(kf1[i]); h[4+i] = p1.h; l[4+i] = p1.l;
            }
            *(bf16x8*)(Khi + skey*KSTRIDE + sd0) = h;
            *(bf16x8*)(Klo + skey*KSTRIDE + sd0) = l;
            bf16x8 vh, vl;
            #pragma unroll
            for (int i = 0; i < 8; ++i) {
                bfpair p = splitf(vf[i]); vh[i] = p.h; vl[i] = p.l;
            }
            *(bf16x8*)(Vhi + svd*VSTRIDE + svk0) = vh;
            *(bf16x8*)(Vlo + svd*VSTRIDE + svk0) = vl;
        }
        __syncthreads();                       // staging visible
        if (ct < 31) { // register prefetch of next tile, overlaps compute
            const int nk = key0 + 32;
            const float* ksrc = xbase + (size_t)(nk + skey) * XROW + sd0;
            kf0 = *(const floatx4*)ksrc;
            kf1 = *(const floatx4*)(ksrc + 4);
            const float* vsrc = xbase + (size_t)(nk + svk0) * XROW + svd;
            #pragma unroll
            for (int i = 0; i < 8; ++i) vf[i] = vsrc[i * XROW];
        }
        // adj prefetch (L2/L3-hot, issued before the MFMA burst)
        float av[2][2][4];
        #pragma unroll
        for (int mt = 0; mt < 2; ++mt)
            #pragma unroll
            for (int nt = 0; nt < 2; ++nt)
                #pragma unroll
                for (int r = 0; r < 4; ++r)
                    av[mt][nt][r] = adj[(size_t)(row0 + wave*32 + mt*16 + quad*4 + r) * NNODE
                                        + key0 + nt*16 + l16];

        // ---- S = Q K^T (3-term split bf16) ----
        floatx4 S[2][2] = {{vzero, vzero}, {vzero, vzero}};
        #pragma unroll
        for (int ks = 0; ks < 2; ++ks) {
            #pragma unroll
            for (int nt = 0; nt < 2; ++nt) {
                bf16x8 bh = *(const bf16x8*)(Khi + (nt*16 + l16)*KSTRIDE + ks*32 + quad*8);
                bf16x8 bl = *(const bf16x8*)(Klo + (nt*16 + l16)*KSTRIDE + ks*32 + quad*8);
                #pragma unroll
                for (int mt = 0; mt < 2; ++mt) {
                    S[mt][nt] = MFMA(qhi[mt][ks], bh, S[mt][nt]);
                    S[mt][nt] = MFMA(qlo[mt][ks], bh, S[mt][nt]);
                    S[mt][nt] = MFMA(qhi[mt][ks], bl, S[mt][nt]);
                }
            }
        }
        // ---- exp, denominator, P = adj*exp -> LDS (own wave's rows only) ----
        #pragma unroll
        for (int mt = 0; mt < 2; ++mt)
            #pragma unroll
            for (int nt = 0; nt < 2; ++nt)
                #pragma unroll
                for (int r = 0; r < 4; ++r) {
                    float w = __expf(S[mt][nt][r] * 0.125f);
                    lpart[mt][r] += w;
                    Pm[(wave*32 + mt*16 + quad*4 + r)*PSTRIDE + nt*16 + l16] = av[mt][nt][r] * w;
                }
        // ---- agg += P . V (3-term split; P A-frags read back from LDS) ----
        bf16x8 pah[2], pal[2];
        #pragma unroll
        for (int mt = 0; mt < 2; ++mt) {
            const float* pp = Pm + (wave*32 + mt*16 + l16)*PSTRIDE + quad*8;
            floatx4 p0 = *(const floatx4*)pp;
            floatx4 p1 = *(const floatx4*)(pp + 4);
            #pragma unroll
            for (int i = 0; i < 4; ++i) {
                bfpair q0 = splitf(p0[i]); pah[mt][i]   = q0.h; pal[mt][i]   = q0.l;
                bfpair q1 = splitf(p1[i]); pah[mt][4+i] = q1.h; pal[mt][4+i] = q1.l;
            }
        }
        #pragma unroll
        for (int dt = 0; dt < 4; ++dt) {
            bf16x8 vh = *(const bf16x8*)(Vhi + (dt*16 + l16)*VSTRIDE + quad*8);
            bf16x8 vl = *(const bf16x8*)(Vlo + (dt*16 + l16)*VSTRIDE + quad*8);
            #pragma unroll
            for (int mt = 0; mt < 2; ++mt) {
                acc[mt][dt] = MFMA(pah[mt], vh, acc[mt][dt]);
                acc[mt][dt] = MFMA(pal[mt], vh, acc[mt][dt]);
                acc[mt][dt] = MFMA(pah[mt], vl, acc[mt][dt]);
            }
        }
    }

    // ---- denominator reduce across the 16 lanes of each quad-group ----
    float linv[2][4];
    #pragma unroll
    for (int mt = 0; mt < 2; ++mt)
        #pragma unroll
        for (int r = 0; r < 4; ++r) {
            float lv = lpart[mt][r];
            lv += __shfl_xor(lv, 1);
            lv += __shfl_xor(lv, 2);
            lv += __shfl_xor(lv, 4);
            lv += __shfl_xor(lv, 8);
            linv[mt][r] = 1.0f / lv;
        }

    // ---- epilogue: out = relu((agg/l) @ theta), split-bf16 MFMA ----
    __syncthreads();                           // everyone done with K/V/P
    float* AG = (float*)smem;                  // [128][AGSTRIDE] overlay
    #pragma unroll
    for (int mt = 0; mt < 2; ++mt)
        #pragma unroll
        for (int dt = 0; dt < 4; ++dt)
            #pragma unroll
            for (int r = 0; r < 4; ++r)
                AG[(wave*32 + mt*16 + quad*4 + r)*AGSTRIDE + dt*16 + l16]
                    = acc[mt][dt][r] * linv[mt][r];

    bf16x8 th[4][2], tl[4][2];                 // theta B-frags (hi/lo)
    #pragma unroll
    for (int ot = 0; ot < 4; ++ot)
        #pragma unroll
        for (int ks = 0; ks < 2; ++ks)
            #pragma unroll
            for (int j = 0; j < 8; ++j) {
                float tv = theta[(ks*32 + quad*8 + j)*ND + ot*16 + l16];
                bfpair p = splitf(tv);
                th[ot][ks][j] = p.h; tl[ot][ks][j] = p.l;
            }

    floatx4 oacc[2][4];
    #pragma unroll
    for (int mt = 0; mt < 2; ++mt)
        #pragma unroll
        for (int ot = 0; ot < 4; ++ot)
            oacc[mt][ot] = vzero;
    __syncthreads();                           // AG visible to all waves
    #pragma unroll
    for (int ks = 0; ks < 2; ++ks) {
        bf16x8 ah[2], al[2];
        #pragma unroll
        for (int mt = 0; mt < 2; ++mt) {
            const float* ap = AG + (wave*32 + mt*16 + l16)*AGSTRIDE + ks*32 + quad*8;
            floatx4 a0 = *(const floatx4*)ap;
            floatx4 a1 = *(const floatx4*)(ap + 4);
            #pragma unroll
            for (int i = 0; i < 4; ++i) {
                bfpair q0 = splitf(a0[i]); ah[mt][i]   = q0.h; al[mt][i]   = q0.l;
                bfpair q1 = splitf(a1[i]); ah[mt][4+i] = q1.h; al[mt][4+i] = q1.l;
            }
        }
        #pragma unroll
        for (int ot = 0; ot < 4; ++ot)
            #pragma unroll
            for (int mt = 0; mt < 2; ++mt) {
                oacc[mt][ot] = MFMA(ah[mt], th[ot][ks], oacc[mt][ot]);
                oacc[mt][ot] = MFMA(al[mt], th[ot][ks], oacc[mt][ot]);
                oacc[mt][ot] = MFMA(ah[mt], tl[ot][ks], oacc[mt][ot]);
            }
    }

    float* obase = out + (size_t)bb * (NNODE * XROW) + tt * ND;
    #pragma unroll
    for (int mt = 0; mt < 2; ++mt)
        #pragma unroll
        for (int ot = 0; ot < 4; ++ot)
            #pragma unroll
            for (int r = 0; r < 4; ++r) {
                float v = oacc[mt][ot][r];
                obase[(size_t)(row0 + wave*32 + mt*16 + quad*4 + r) * XROW + ot*16 + l16]
                    = v > 0.f ? v : 0.f;
            }
}

extern "C" void kernel_launch(void* const* d_in, const int* in_sizes, int n_in,
                              void* d_out, int out_size, void* d_ws, size_t ws_size,
                              hipStream_t stream) {
    (void)in_sizes; (void)n_in; (void)d_ws; (void)ws_size; (void)out_size;
    const float* x     = (const float*)d_in[0];
    const float* adj   = (const float*)d_in[1];
    const float* theta = (const float*)d_in[2];
    float* out = (float*)d_out;
    spattn<<<dim3(768), dim3(256), 0, stream>>>(x, adj, theta, out);
}

// Round 5
// 171.044 us; speedup vs baseline: 1.0809x; 1.0809x over previous
//
#include <hip/hip_runtime.h>

// PositionWiseSpatialAttention — fused flash-style kernel, MI355X gfx950.
//
// R5 = R4 intent, compile-fixed with the R2-proven pattern: split returns a
// by-value {hi,lo} pair (no references to vector elements). Native __bf16
// casts (RNE fptrunc -> v_cvt_pk_bf16_f32 when paired), ~3-4 VALU/elem vs 9
// in R2's splitf. Softmax scale folded into Q (0.125*log2e) + exp2 direct.
// R2 counters: VALUBusy 54%, MfmaUtil 25.5% -> VALU-bound on split cost;
// this attacks exactly that. Structure/layouts unchanged from R2.

#define NB    8
#define NT    12
#define NNODE 1024
#define ND    64
#define XROW  768   /* NT*ND: stride between consecutive n for fixed (b,t) */

typedef __bf16 bf16x8 __attribute__((ext_vector_type(8)));
typedef float  floatx4 __attribute__((ext_vector_type(4)));

#define MFMA(a,b,c) __builtin_amdgcn_mfma_f32_16x16x32_bf16((a),(b),(c),0,0,0)

#define QSCALE 0.18033688011112042f   /* 0.125 * log2(e) */

// LDS layout (bytes); all row strides keep 16B alignment for b128 ops.
#define KSTRIDE 72   /* bf16 per K row: 144 B */
#define VSTRIDE 40   /* bf16 per V row:  80 B */
#define PSTRIDE 36   /* f32  per P row: 144 B */
#define AGSTRIDE 68  /* f32  per AG row (epilogue overlay) */
#define OFF_KHI 0
#define OFF_KLO 4608
#define OFF_VHI 9216
#define OFF_VLO 14336
#define OFF_P   19456
#define SMEM_BYTES (19456 + 128*PSTRIDE*4)   /* 37888 */

struct bfpair { __bf16 h, l; };

// error-compensated split: hi = RNE(f) via native fptrunc, lo = RNE(f - hi).
// |f - hi - lo| ~ 2^-17 |f|.
__device__ __forceinline__ bfpair split1(float f) {
    bfpair r;
    __bf16 hb = (__bf16)f;
    float hf = __builtin_bit_cast(float,
                   (unsigned)__builtin_bit_cast(unsigned short, hb) << 16);
    r.h = hb;
    r.l = (__bf16)(f - hf);
    return r;
}

__global__ void __launch_bounds__(256, 2)
spattn(const float* __restrict__ x, const float* __restrict__ adj,
       const float* __restrict__ theta, float* __restrict__ out)
{
    __shared__ __align__(16) char smem[SMEM_BYTES];
    __bf16* Khi = (__bf16*)(smem + OFF_KHI);
    __bf16* Klo = (__bf16*)(smem + OFF_KLO);
    __bf16* Vhi = (__bf16*)(smem + OFF_VHI);
    __bf16* Vlo = (__bf16*)(smem + OFF_VLO);
    float*  Pm  = (float*)(smem + OFF_P);

    const int tid  = threadIdx.x;
    const int wave = tid >> 6;
    const int lane = tid & 63;
    const int l16  = lane & 15;
    const int quad = lane >> 4;

    const int bx   = blockIdx.x;
    const int g    = bx >> 3;       // 0..95
    const int rblk = bx & 7;        // 0..7
    const int bb   = g / NT;
    const int tt   = g - bb * NT;
    const int row0 = rblk * 128;

    const float* xbase = x + (size_t)bb * (NNODE * XROW) + tt * ND;

    // ---- Q fragments (hi/lo), pre-scaled by 0.125*log2e, from global ----
    bf16x8 qhi[2][2], qlo[2][2];
    #pragma unroll
    for (int mt = 0; mt < 2; ++mt) {
        const float* qsrc = xbase + (size_t)(row0 + wave*32 + mt*16 + l16) * XROW;
        #pragma unroll
        for (int ks = 0; ks < 2; ++ks) {
            floatx4 f0 = *(const floatx4*)(qsrc + ks*32 + quad*8);
            floatx4 f1 = *(const floatx4*)(qsrc + ks*32 + quad*8 + 4);
            #pragma unroll
            for (int i = 0; i < 4; ++i) {
                bfpair p0 = split1(f0[i]*QSCALE);
                qhi[mt][ks][i]   = p0.h; qlo[mt][ks][i]   = p0.l;
                bfpair p1 = split1(f1[i]*QSCALE);
                qhi[mt][ks][4+i] = p1.h; qlo[mt][ks][4+i] = p1.l;
            }
        }
    }

    const floatx4 vzero = {0.f, 0.f, 0.f, 0.f};
    floatx4 acc[2][4];
    #pragma unroll
    for (int mt = 0; mt < 2; ++mt)
        #pragma unroll
        for (int dt = 0; dt < 4; ++dt)
            acc[mt][dt] = vzero;
    float lpart[2][4] = {{0.f,0.f,0.f,0.f},{0.f,0.f,0.f,0.f}};

    // staging maps: K-map (1 key x 8 d, b128 LDS writes), V-map (8 keys x 1 d)
    const int skey = tid >> 3;          // 0..31
    const int sd0  = (tid & 7) * 8;     // 0..56
    const int svd  = tid >> 2;          // 0..63
    const int svk0 = (tid & 3) * 8;     // 0..24
    floatx4 kf0, kf1;
    float vf[8];

    { // preload tile 0 into registers
        const float* ksrc = xbase + (size_t)skey * XROW + sd0;
        kf0 = *(const floatx4*)ksrc;
        kf1 = *(const floatx4*)(ksrc + 4);
        const float* vsrc = xbase + (size_t)svk0 * XROW + svd;
        #pragma unroll
        for (int i = 0; i < 8; ++i) vf[i] = vsrc[i * XROW];
    }

    for (int ct = 0; ct < 32; ++ct) {
        const int key0 = ct * 32;
        __syncthreads();                       // prior tile's LDS reads done
        { // store staged tile (split hi/lo) to LDS
            bf16x8 h, l;
            #pragma unroll
            for (int i = 0; i < 4; ++i) {
                bfpair p0 = split1(kf0[i]); h[i]   = p0.h; l[i]   = p0.l;
                bfpair p1 = split1(kf1[i]); h[4+i] = p1.h; l[4+i] = p1.l;
            }
            *(bf16x8*)(Khi + skey*KSTRIDE + sd0) = h;
            *(bf16x8*)(Klo + skey*KSTRIDE + sd0) = l;
            bf16x8 vh, vl;
            #pragma unroll
            for (int i = 0; i < 8; ++i) {
                bfpair p = split1(vf[i]); vh[i] = p.h; vl[i] = p.l;
            }
            *(bf16x8*)(Vhi + svd*VSTRIDE + svk0) = vh;
            *(bf16x8*)(Vlo + svd*VSTRIDE + svk0) = vl;
        }
        __syncthreads();                       // staging visible
        if (ct < 31) { // register prefetch of next tile, overlaps compute
            const int nk = key0 + 32;
            const float* ksrc = xbase + (size_t)(nk + skey) * XROW + sd0;
            kf0 = *(const floatx4*)ksrc;
            kf1 = *(const floatx4*)(ksrc + 4);
            const float* vsrc = xbase + (size_t)(nk + svk0) * XROW + svd;
            #pragma unroll
            for (int i = 0; i < 8; ++i) vf[i] = vsrc[i * XROW];
        }
        // adj prefetch (L2/L3-hot, issued before the MFMA burst)
        float av[2][2][4];
        #pragma unroll
        for (int mt = 0; mt < 2; ++mt)
            #pragma unroll
            for (int nt = 0; nt < 2; ++nt)
                #pragma unroll
                for (int r = 0; r < 4; ++r)
                    av[mt][nt][r] = adj[(size_t)(row0 + wave*32 + mt*16 + quad*4 + r) * NNODE
                                        + key0 + nt*16 + l16];

        // ---- S = Q K^T (3-term split bf16); S is pre-scaled for exp2 ----
        floatx4 S[2][2] = {{vzero, vzero}, {vzero, vzero}};
        #pragma unroll
        for (int ks = 0; ks < 2; ++ks) {
            #pragma unroll
            for (int nt = 0; nt < 2; ++nt) {
                bf16x8 bh = *(const bf16x8*)(Khi + (nt*16 + l16)*KSTRIDE + ks*32 + quad*8);
                bf16x8 bl = *(const bf16x8*)(Klo + (nt*16 + l16)*KSTRIDE + ks*32 + quad*8);
                #pragma unroll
                for (int mt = 0; mt < 2; ++mt) {
                    S[mt][nt] = MFMA(qhi[mt][ks], bh, S[mt][nt]);
                    S[mt][nt] = MFMA(qlo[mt][ks], bh, S[mt][nt]);
                    S[mt][nt] = MFMA(qhi[mt][ks], bl, S[mt][nt]);
                }
            }
        }
        // ---- exp2, denominator, P = adj*exp -> LDS (own wave's rows) ----
        #pragma unroll
        for (int mt = 0; mt < 2; ++mt)
            #pragma unroll
            for (int nt = 0; nt < 2; ++nt)
                #pragma unroll
                for (int r = 0; r < 4; ++r) {
                    float w = __builtin_amdgcn_exp2f(S[mt][nt][r]);
                    lpart[mt][r] += w;
                    Pm[(wave*32 + mt*16 + quad*4 + r)*PSTRIDE + nt*16 + l16] = av[mt][nt][r] * w;
                }
        // ---- agg += P . V (3-term split; P A-frags read back from LDS) ----
        bf16x8 pah[2], pal[2];
        #pragma unroll
        for (int mt = 0; mt < 2; ++mt) {
            const float* pp = Pm + (wave*32 + mt*16 + l16)*PSTRIDE + quad*8;
            floatx4 p0 = *(const floatx4*)pp;
            floatx4 p1 = *(const floatx4*)(pp + 4);
            #pragma unroll
            for (int i = 0; i < 4; ++i) {
                bfpair q0 = split1(p0[i]); pah[mt][i]   = q0.h; pal[mt][i]   = q0.l;
                bfpair q1 = split1(p1[i]); pah[mt][4+i] = q1.h; pal[mt][4+i] = q1.l;
            }
        }
        #pragma unroll
        for (int dt = 0; dt < 4; ++dt) {
            bf16x8 vh = *(const bf16x8*)(Vhi + (dt*16 + l16)*VSTRIDE + quad*8);
            bf16x8 vl = *(const bf16x8*)(Vlo + (dt*16 + l16)*VSTRIDE + quad*8);
            #pragma unroll
            for (int mt = 0; mt < 2; ++mt) {
                acc[mt][dt] = MFMA(pah[mt], vh, acc[mt][dt]);
                acc[mt][dt] = MFMA(pal[mt], vh, acc[mt][dt]);
                acc[mt][dt] = MFMA(pah[mt], vl, acc[mt][dt]);
            }
        }
    }

    // ---- denominator reduce across the 16 lanes of each quad-group ----
    float linv[2][4];
    #pragma unroll
    for (int mt = 0; mt < 2; ++mt)
        #pragma unroll
        for (int r = 0; r < 4; ++r) {
            float lv = lpart[mt][r];
            lv += __shfl_xor(lv, 1);
            lv += __shfl_xor(lv, 2);
            lv += __shfl_xor(lv, 4);
            lv += __shfl_xor(lv, 8);
            linv[mt][r] = 1.0f / lv;
        }

    // ---- epilogue: out = relu((agg/l) @ theta), split-bf16 MFMA ----
    __syncthreads();                           // everyone done with K/V/P
    float* AG = (float*)smem;                  // [128][AGSTRIDE] overlay
    #pragma unroll
    for (int mt = 0; mt < 2; ++mt)
        #pragma unroll
        for (int dt = 0; dt < 4; ++dt)
            #pragma unroll
            for (int r = 0; r < 4; ++r)
                AG[(wave*32 + mt*16 + quad*4 + r)*AGSTRIDE + dt*16 + l16]
                    = acc[mt][dt][r] * linv[mt][r];

    bf16x8 th[4][2], tl[4][2];                 // theta B-frags (hi/lo)
    #pragma unroll
    for (int ot = 0; ot < 4; ++ot)
        #pragma unroll
        for (int ks = 0; ks < 2; ++ks)
            #pragma unroll
            for (int j = 0; j < 8; ++j) {
                float tv = theta[(ks*32 + quad*8 + j)*ND + ot*16 + l16];
                bfpair p = split1(tv);
                th[ot][ks][j] = p.h; tl[ot][ks][j] = p.l;
            }

    floatx4 oacc[2][4];
    #pragma unroll
    for (int mt = 0; mt < 2; ++mt)
        #pragma unroll
        for (int ot = 0; ot < 4; ++ot)
            oacc[mt][ot] = vzero;
    __syncthreads();                           // AG visible to all waves
    #pragma unroll
    for (int ks = 0; ks < 2; ++ks) {
        bf16x8 ah[2], al[2];
        #pragma unroll
        for (int mt = 0; mt < 2; ++mt) {
            const float* ap = AG + (wave*32 + mt*16 + l16)*AGSTRIDE + ks*32 + quad*8;
            floatx4 a0 = *(const floatx4*)ap;
            floatx4 a1 = *(const floatx4*)(ap + 4);
            #pragma unroll
            for (int i = 0; i < 4; ++i) {
                bfpair q0 = split1(a0[i]); ah[mt][i]   = q0.h; al[mt][i]   = q0.l;
                bfpair q1 = split1(a1[i]); ah[mt][4+i] = q1.h; al[mt][4+i] = q1.l;
            }
        }
        #pragma unroll
        for (int ot = 0; ot < 4; ++ot)
            #pragma unroll
            for (int mt = 0; mt < 2; ++mt) {
                oacc[mt][ot] = MFMA(ah[mt], th[ot][ks], oacc[mt][ot]);
                oacc[mt][ot] = MFMA(al[mt], th[ot][ks], oacc[mt][ot]);
                oacc[mt][ot] = MFMA(ah[mt], tl[ot][ks], oacc[mt][ot]);
            }
    }

    float* obase = out + (size_t)bb * (NNODE * XROW) + tt * ND;
    #pragma unroll
    for (int mt = 0; mt < 2; ++mt)
        #pragma unroll
        for (int ot = 0; ot < 4; ++ot)
            #pragma unroll
            for (int r = 0; r < 4; ++r) {
                float v = oacc[mt][ot][r];
                obase[(size_t)(row0 + wave*32 + mt*16 + quad*4 + r) * XROW + ot*16 + l16]
                    = v > 0.f ? v : 0.f;
            }
}

extern "C" void kernel_launch(void* const* d_in, const int* in_sizes, int n_in,
                              void* d_out, int out_size, void* d_ws, size_t ws_size,
                              hipStream_t stream) {
    (void)in_sizes; (void)n_in; (void)d_ws; (void)ws_size; (void)out_size;
    const float* x     = (const float*)d_in[0];
    const float* adj   = (const float*)d_in[1];
    const float* theta = (const float*)d_in[2];
    float* out = (float*)d_out;
    spattn<<<dim3(768), dim3(256), 0, stream>>>(x, adj, theta, out);
}